// Round 5
// baseline (1315.915 us; speedup 1.0000x reference)
//
#include <hip/hip_runtime.h>
#include <hip/hip_bf16.h>

#define BATCH 16
#define NPTS  4096
#define NSAMP 1024   // S = N * 0.25
#define KNB   32     // nsample
#define DFEAT 64

#define FPS_T   256
#define FPS_PPT (NPTS / FPS_T)   // 16 points per thread
#define FPS_W   (FPS_T / 64)     // 4 waves

// ---------------------------------------------------------------------------
// DPP wave64 argmax round on packed u64 key, carrying (x,y,z) payload.
// Key = (f32_bits(value) << 32) | ~idx : max key == max value, ties -> min idx.
// ctrl/rmask must be compile-time constants -> template parameters.
// ---------------------------------------------------------------------------
template <int CTRL, int RMASK>
__device__ __forceinline__ void dpp_round(unsigned long long& key, float& x, float& y,
                                          float& z) {
    const int klo = (int)(unsigned)key;
    const int khi = (int)(unsigned)(key >> 32);
    const int tlo = __builtin_amdgcn_update_dpp(klo, klo, CTRL, RMASK, 0xF, false);
    const int thi = __builtin_amdgcn_update_dpp(khi, khi, CTRL, RMASK, 0xF, false);
    const int tx  = __builtin_amdgcn_update_dpp(__float_as_int(x), __float_as_int(x), CTRL, RMASK, 0xF, false);
    const int ty  = __builtin_amdgcn_update_dpp(__float_as_int(y), __float_as_int(y), CTRL, RMASK, 0xF, false);
    const int tz  = __builtin_amdgcn_update_dpp(__float_as_int(z), __float_as_int(z), CTRL, RMASK, 0xF, false);
    const unsigned long long tk =
        ((unsigned long long)(unsigned)thi << 32) | (unsigned)tlo;
    if (tk > key) {
        key = tk;
        x = __int_as_float(tx);
        y = __int_as_float(ty);
        z = __int_as_float(tz);
    }
}

// ---------------------------------------------------------------------------
// Kernel 1: farthest point sampling. One block per batch, 256 threads.
// Coords + min_d in registers; winner coords carried through the reduce
// (no indexed centroid lookup); outputs staged in LDS, flushed at end
// (no global stores inside the serial loop).
// ---------------------------------------------------------------------------
__global__ __launch_bounds__(FPS_T) void fps_kernel(const float* __restrict__ xyz,
                                                    float* __restrict__ out_xyz) {
    const int b    = blockIdx.x;
    const int tid  = threadIdx.x;
    const int lane = tid & 63;
    const int wid  = tid >> 6;

    __shared__ float stX[NSAMP], stY[NSAMP], stZ[NSAMP];   // 12 KB output staging
    __shared__ uint4 pA[2][FPS_W];                         // key_lo, key_hi, x, y
    __shared__ float pZ[2][FPS_W];

    float px[FPS_PPT], py[FPS_PPT], pz[FPS_PPT], md[FPS_PPT];

    const float* base = xyz + (size_t)b * NPTS * 3;
#pragma unroll
    for (int j = 0; j < FPS_PPT; j++) {
        const int i = j * FPS_T + tid;
        px[j] = base[i * 3 + 0];
        py[j] = base[i * 3 + 1];
        pz[j] = base[i * 3 + 2];
        md[j] = 1e10f;
    }

    // initial centroid = point 0 (broadcast global read, L2-cached)
    float cx = base[0], cy = base[1], cz = base[2];
    if (tid == 0) { stX[0] = cx; stY[0] = cy; stZ[0] = cz; }

    for (int s = 1; s < NSAMP; s++) {
        float best = -1.0f;
        int   bi   = 0;
        float bx = 0.0f, by = 0.0f, bz = 0.0f;
#pragma unroll
        for (int j = 0; j < FPS_PPT; j++) {
            const float dx = px[j] - cx;
            const float dy = py[j] - cy;
            const float dz = pz[j] - cz;
            // match reference rounding: no fma contraction
            const float d = __fadd_rn(__fadd_rn(__fmul_rn(dx, dx), __fmul_rn(dy, dy)),
                                      __fmul_rn(dz, dz));
            const float m = fminf(md[j], d);
            md[j] = m;
            if (m > best) { best = m; bi = j * FPS_T + tid; bx = px[j]; by = py[j]; bz = pz[j]; }
        }
        // pack (value, ~idx); min_d >= 0 so u32-bits compare == float compare
        unsigned long long key =
            ((unsigned long long)__float_as_uint(best) << 32) | (unsigned)(~bi);
        dpp_round<0x111, 0xF>(key, bx, by, bz);  // row_shr:1
        dpp_round<0x112, 0xF>(key, bx, by, bz);  // row_shr:2
        dpp_round<0x114, 0xF>(key, bx, by, bz);  // row_shr:4
        dpp_round<0x118, 0xF>(key, bx, by, bz);  // row_shr:8
        dpp_round<0x142, 0xA>(key, bx, by, bz);  // row_bcast:15
        dpp_round<0x143, 0xC>(key, bx, by, bz);  // row_bcast:31 -> lane 63 = wave max

        const int par = s & 1;
        if (lane == 63) {
            pA[par][wid] = make_uint4((unsigned)key, (unsigned)(key >> 32),
                                      __float_as_uint(bx), __float_as_uint(by));
            pZ[par][wid] = bz;
        }
        __syncthreads();
        // every thread redundantly reduces the 4 wave partials (broadcast reads)
        uint4 w0 = pA[par][0];
        unsigned long long bk = ((unsigned long long)w0.y << 32) | w0.x;
        cx = __uint_as_float(w0.z);
        cy = __uint_as_float(w0.w);
        cz = pZ[par][0];
#pragma unroll
        for (int w = 1; w < FPS_W; w++) {
            const uint4 ww = pA[par][w];
            const unsigned long long k2 = ((unsigned long long)ww.y << 32) | ww.x;
            if (k2 > bk) {
                bk = k2;
                cx = __uint_as_float(ww.z);
                cy = __uint_as_float(ww.w);
                cz = pZ[par][w];
            }
        }
        if (tid == 0) { stX[s] = cx; stY[s] = cy; stZ[s] = cz; }
    }

    __syncthreads();
    float* ob = out_xyz + (size_t)b * 3 * NSAMP;
    for (int i = tid; i < NSAMP; i += FPS_T) {
        ob[0 * NSAMP + i] = stX[i];
        ob[1 * NSAMP + i] = stY[i];
        ob[2 * NSAMP + i] = stZ[i];
    }
}

// ---------------------------------------------------------------------------
// Kernel 2: ball query. One wave (64 lanes) per query point.
// Centers read from new_xyz (out_xyz) -- fps_idx no longer exists.
// ---------------------------------------------------------------------------
__global__ __launch_bounds__(256) void ballq_kernel(const float* __restrict__ xyz,
                                                    const float* __restrict__ new_xyz,
                                                    int* __restrict__ grp) {
    const int q    = blockIdx.x * 4 + (threadIdx.x >> 6);
    const int lane = threadIdx.x & 63;
    const int b    = q >> 10;       // / NSAMP
    const int sq   = q & 1023;

    const float* nb = new_xyz + (size_t)b * 3 * NSAMP;
    const float cx = nb[0 * NSAMP + sq];
    const float cy = nb[1 * NSAMP + sq];
    const float cz = nb[2 * NSAMP + sq];
    const float r2 = 0.04f;         // f32(0.2*0.2)

    const float* base = xyz + (size_t)b * NPTS * 3;
    int* g = grp + (size_t)q * KNB;
    int cnt = 0;
    int firstCand = 0x7fffffff;

    for (int bp = 0; bp < NPTS && cnt < KNB; bp += 64) {
        const int p = bp + lane;
        const float dx = base[p * 3 + 0] - cx;
        const float dy = base[p * 3 + 1] - cy;
        const float dz = base[p * 3 + 2] - cz;
        const float d = __fadd_rn(__fadd_rn(__fmul_rn(dx, dx), __fmul_rn(dy, dy)),
                                  __fmul_rn(dz, dz));
        const bool ok = !(d > r2);
        const unsigned long long m = __ballot(ok);
        const int rank = cnt + (int)__popcll(m & ((1ull << lane) - 1ull));
        if (ok && rank < KNB) g[rank] = p;
        if (ok && rank == 0) firstCand = p;
        cnt += (int)__popcll(m);
    }

    const int found = cnt < KNB ? cnt : KNB;
    if (found < KNB) {
#pragma unroll
        for (int off = 32; off > 0; off >>= 1) {
            const int o = __shfl_xor(firstCand, off);
            firstCand = o < firstCand ? o : firstCand;
        }
        for (int r = found + lane; r < KNB; r += 64) g[r] = firstCand;
    }
}

// ---------------------------------------------------------------------------
// Kernel 3: gather + MLP(64->64 relu, 64->128 relu) + max over 32 samples.
// One wave per query; lane = channel. All LDS traffic is wave-local
// (xls[wid], h1s[wid]) -> NO barriers needed; intra-wave DS ordering +
// compiler lgkmcnt waits guarantee correctness.
// ---------------------------------------------------------------------------
__global__ __launch_bounds__(256) void mlp_kernel(const float* __restrict__ features,
                                                  const int* __restrict__ grp,
                                                  const float* __restrict__ W1,
                                                  const float* __restrict__ b1,
                                                  const float* __restrict__ W2,
                                                  const float* __restrict__ b2,
                                                  float* __restrict__ out_pts) {
    const int wid  = threadIdx.x >> 6;
    const int lane = threadIdx.x & 63;
    const int q    = blockIdx.x * 4 + wid;
    const int b    = q >> 10;
    const int s    = q & 1023;

    __shared__ float xls[4][KNB][DFEAT];   // 32 KB, wave-local
    __shared__ float h1s[4][DFEAT];        // 1 KB, wave-local

    float w1r[64], w2ra[64], w2rb[64];
    {
        const float4* W1v = (const float4*)(W1 + (size_t)lane * 64);
        const float4* W2a = (const float4*)(W2 + (size_t)lane * 64);
        const float4* W2b = (const float4*)(W2 + (size_t)(lane + 64) * 64);
#pragma unroll
        for (int i = 0; i < 16; i++) {
            float4 v = W1v[i];
            w1r[4 * i] = v.x; w1r[4 * i + 1] = v.y; w1r[4 * i + 2] = v.z; w1r[4 * i + 3] = v.w;
            v = W2a[i];
            w2ra[4 * i] = v.x; w2ra[4 * i + 1] = v.y; w2ra[4 * i + 2] = v.z; w2ra[4 * i + 3] = v.w;
            v = W2b[i];
            w2rb[4 * i] = v.x; w2rb[4 * i + 1] = v.y; w2rb[4 * i + 2] = v.z; w2rb[4 * i + 3] = v.w;
        }
    }
    const float b1r  = b1[lane];
    const float b2ra = b2[lane];
    const float b2rb = b2[lane + 64];

    int gi = 0;
    if (lane < KNB) gi = grp[(size_t)q * KNB + lane];
    const float* fb = features + (size_t)b * NPTS * DFEAT;
    for (int k = 0; k < KNB; k++) {
        const int idxk = __shfl(gi, k);
        xls[wid][k][lane] = fb[(size_t)idxk * DFEAT + lane];
    }

    float m0 = 0.0f, m1 = 0.0f;   // relu outputs >= 0
    for (int k = 0; k < KNB; k++) {
        float acc = b1r;
        const float4* xk = (const float4*)xls[wid][k];
#pragma unroll
        for (int i = 0; i < 16; i++) {
            const float4 v = xk[i];
            acc = fmaf(v.x, w1r[4 * i], acc);
            acc = fmaf(v.y, w1r[4 * i + 1], acc);
            acc = fmaf(v.z, w1r[4 * i + 2], acc);
            acc = fmaf(v.w, w1r[4 * i + 3], acc);
        }
        h1s[wid][lane] = fmaxf(acc, 0.0f);
        float a0 = b2ra, a1 = b2rb;
        const float4* hv4 = (const float4*)h1s[wid];
#pragma unroll
        for (int i = 0; i < 16; i++) {
            const float4 v = hv4[i];
            a0 = fmaf(v.x, w2ra[4 * i], a0);
            a0 = fmaf(v.y, w2ra[4 * i + 1], a0);
            a0 = fmaf(v.z, w2ra[4 * i + 2], a0);
            a0 = fmaf(v.w, w2ra[4 * i + 3], a0);
            a1 = fmaf(v.x, w2rb[4 * i], a1);
            a1 = fmaf(v.y, w2rb[4 * i + 1], a1);
            a1 = fmaf(v.z, w2rb[4 * i + 2], a1);
            a1 = fmaf(v.w, w2rb[4 * i + 3], a1);
        }
        m0 = fmaxf(m0, fmaxf(a0, 0.0f));
        m1 = fmaxf(m1, fmaxf(a1, 0.0f));
    }

    out_pts[(size_t)b * 128 * NSAMP + (size_t)lane * NSAMP + s]        = m0;
    out_pts[(size_t)b * 128 * NSAMP + (size_t)(lane + 64) * NSAMP + s] = m1;
}

extern "C" void kernel_launch(void* const* d_in, const int* in_sizes, int n_in,
                              void* d_out, int out_size, void* d_ws, size_t ws_size,
                              hipStream_t stream) {
    const float* xyz      = (const float*)d_in[0];
    const float* features = (const float*)d_in[1];
    const float* W1       = (const float*)d_in[2];
    const float* b1       = (const float*)d_in[3];
    const float* W2       = (const float*)d_in[4];
    const float* b2       = (const float*)d_in[5];

    float* out_xyz = (float*)d_out;                                  // [B,3,S]
    float* out_pts = (float*)d_out + (size_t)BATCH * 3 * NSAMP;      // [B,128,S]

    int* grp = (int*)d_ws;                                           // [B,S,32]

    fps_kernel<<<BATCH, FPS_T, 0, stream>>>(xyz, out_xyz);
    ballq_kernel<<<BATCH * NSAMP / 4, 256, 0, stream>>>(xyz, out_xyz, grp);
    mlp_kernel<<<BATCH * NSAMP / 4, 256, 0, stream>>>(features, grp, W1, b1, W2, b2, out_pts);
}

// Round 6
// 876.251 us; speedup vs baseline: 1.5018x; 1.5018x over previous
//
#include <hip/hip_runtime.h>
#include <hip/hip_bf16.h>

#define BATCH 16
#define NPTS  4096
#define NSAMP 1024   // S = N * 0.25
#define KNB   32     // nsample
#define DFEAT 64

#define FPS_T   256
#define FPS_PPT (NPTS / FPS_T)   // 16 points per thread
#define FPS_W   (FPS_T / 64)     // 4 waves

// ---------------------------------------------------------------------------
// DPP wave64 max-reduce round on packed u64 key (key-only: 2 DPP + cmp + sel).
// Key = (f32_bits(value) << 32) | ~idx : max key == max value, ties -> min idx.
// Result valid in lane 63. ctrl/rmask are template params (must be constants).
// ---------------------------------------------------------------------------
template <int CTRL, int RMASK>
__device__ __forceinline__ void dpp_round(unsigned long long& key) {
    const int klo = (int)(unsigned)key;
    const int khi = (int)(unsigned)(key >> 32);
    const int tlo = __builtin_amdgcn_update_dpp(klo, klo, CTRL, RMASK, 0xF, false);
    const int thi = __builtin_amdgcn_update_dpp(khi, khi, CTRL, RMASK, 0xF, false);
    const unsigned long long tk =
        ((unsigned long long)(unsigned)thi << 32) | (unsigned)tlo;
    if (tk > key) key = tk;
}

// ---------------------------------------------------------------------------
// Kernel 1: farthest point sampling. One block per batch, 256 threads.
// Coords + min_d in registers; key-only DPP wave reduce; single barrier/step;
// centroid lookup = one broadcast ds_read_b128 from packed float4 LDS coords;
// outputs staged in LDS, flushed at end (no global stores in the serial loop).
// ---------------------------------------------------------------------------
__global__ __launch_bounds__(FPS_T) void fps_kernel(const float* __restrict__ xyz,
                                                    float* __restrict__ out_xyz) {
    const int b    = blockIdx.x;
    const int tid  = threadIdx.x;
    const int lane = tid & 63;
    const int wid  = tid >> 6;

    __shared__ float4 sc[NPTS];                           // 64 KB packed coords
    __shared__ float stX[NSAMP], stY[NSAMP], stZ[NSAMP];  // 12 KB output staging
    __shared__ alignas(16) unsigned long long pw[2][FPS_W];  // wave partials, dbuf

    float px[FPS_PPT], py[FPS_PPT], pz[FPS_PPT], md[FPS_PPT];

    const float* base = xyz + (size_t)b * NPTS * 3;
#pragma unroll
    for (int j = 0; j < FPS_PPT; j++) {
        const int i = j * FPS_T + tid;
        const float x = base[i * 3 + 0];
        const float y = base[i * 3 + 1];
        const float z = base[i * 3 + 2];
        sc[i] = make_float4(x, y, z, 0.0f);
        px[j] = x; py[j] = y; pz[j] = z;
        md[j] = 1e10f;
    }

    // initial centroid = point 0
    float cx = base[0], cy = base[1], cz = base[2];
    if (tid == 0) { stX[0] = cx; stY[0] = cy; stZ[0] = cz; }
    __syncthreads();

    for (int s = 1; s < NSAMP; s++) {
        float best = -1.0f;
        int   bj   = 0;
#pragma unroll
        for (int j = 0; j < FPS_PPT; j++) {
            const float dx = px[j] - cx;
            const float dy = py[j] - cy;
            const float dz = pz[j] - cz;
            // match reference rounding: no fma contraction
            const float d = __fadd_rn(__fadd_rn(__fmul_rn(dx, dx), __fmul_rn(dy, dy)),
                                      __fmul_rn(dz, dz));
            const float m = fminf(md[j], d);
            md[j] = m;
            if (m > best) { best = m; bj = j; }   // strict >: lowest j (lowest idx) wins
        }
        const int bi = (bj << 8) | tid;           // j*256 + tid (disjoint bits)
        // pack (value, ~idx); min_d >= 0 so u32-bits compare == float compare
        unsigned long long key =
            ((unsigned long long)__float_as_uint(best) << 32) | (unsigned)(~bi);
        dpp_round<0x111, 0xF>(key);  // row_shr:1
        dpp_round<0x112, 0xF>(key);  // row_shr:2
        dpp_round<0x114, 0xF>(key);  // row_shr:4
        dpp_round<0x118, 0xF>(key);  // row_shr:8  -> lane15 of each row has row max
        dpp_round<0x142, 0xA>(key);  // row_bcast:15 -> lane31/63 get prior-row max
        dpp_round<0x143, 0xC>(key);  // row_bcast:31 -> lane63 = wave max

        const int par = s & 1;
        if (lane == 63) pw[par][wid] = key;
        __syncthreads();
        // every thread redundantly combines the 4 wave partials (2x b128 reads)
        const ulong2 p01 = *(const ulong2*)&pw[par][0];
        const ulong2 p23 = *(const ulong2*)&pw[par][2];
        unsigned long long bk = p01.x;
        if (p01.y > bk) bk = p01.y;
        if (p23.x > bk) bk = p23.x;
        if (p23.y > bk) bk = p23.y;
        const int bix = (int)(~(unsigned)bk);

        // broadcast lookup of next centroid (single ds_read_b128, same addr)
        const float4 c = sc[bix];
        cx = c.x; cy = c.y; cz = c.z;
        if (tid == 0) { stX[s] = cx; stY[s] = cy; stZ[s] = cz; }
    }

    __syncthreads();
    float* ob = out_xyz + (size_t)b * 3 * NSAMP;
    for (int i = tid; i < NSAMP; i += FPS_T) {
        ob[0 * NSAMP + i] = stX[i];
        ob[1 * NSAMP + i] = stY[i];
        ob[2 * NSAMP + i] = stZ[i];
    }
}

// ---------------------------------------------------------------------------
// Kernel 2: ball query. One wave (64 lanes) per query point.
// Centers read from new_xyz (out_xyz).
// ---------------------------------------------------------------------------
__global__ __launch_bounds__(256) void ballq_kernel(const float* __restrict__ xyz,
                                                    const float* __restrict__ new_xyz,
                                                    int* __restrict__ grp) {
    const int q    = blockIdx.x * 4 + (threadIdx.x >> 6);
    const int lane = threadIdx.x & 63;
    const int b    = q >> 10;       // / NSAMP
    const int sq   = q & 1023;

    const float* nb = new_xyz + (size_t)b * 3 * NSAMP;
    const float cx = nb[0 * NSAMP + sq];
    const float cy = nb[1 * NSAMP + sq];
    const float cz = nb[2 * NSAMP + sq];
    const float r2 = 0.04f;         // f32(0.2*0.2)

    const float* base = xyz + (size_t)b * NPTS * 3;
    int* g = grp + (size_t)q * KNB;
    int cnt = 0;
    int firstCand = 0x7fffffff;

    for (int bp = 0; bp < NPTS && cnt < KNB; bp += 64) {
        const int p = bp + lane;
        const float dx = base[p * 3 + 0] - cx;
        const float dy = base[p * 3 + 1] - cy;
        const float dz = base[p * 3 + 2] - cz;
        const float d = __fadd_rn(__fadd_rn(__fmul_rn(dx, dx), __fmul_rn(dy, dy)),
                                  __fmul_rn(dz, dz));
        const bool ok = !(d > r2);
        const unsigned long long m = __ballot(ok);
        const int rank = cnt + (int)__popcll(m & ((1ull << lane) - 1ull));
        if (ok && rank < KNB) g[rank] = p;
        if (ok && rank == 0) firstCand = p;
        cnt += (int)__popcll(m);
    }

    const int found = cnt < KNB ? cnt : KNB;
    if (found < KNB) {
#pragma unroll
        for (int off = 32; off > 0; off >>= 1) {
            const int o = __shfl_xor(firstCand, off);
            firstCand = o < firstCand ? o : firstCand;
        }
        for (int r = found + lane; r < KNB; r += 64) g[r] = firstCand;
    }
}

// ---------------------------------------------------------------------------
// Kernel 3: gather + MLP(64->64 relu, 64->128 relu) + max over 32 samples.
// One wave per query; lane = channel. All LDS traffic wave-local -> no barriers.
// ---------------------------------------------------------------------------
__global__ __launch_bounds__(256) void mlp_kernel(const float* __restrict__ features,
                                                  const int* __restrict__ grp,
                                                  const float* __restrict__ W1,
                                                  const float* __restrict__ b1,
                                                  const float* __restrict__ W2,
                                                  const float* __restrict__ b2,
                                                  float* __restrict__ out_pts) {
    const int wid  = threadIdx.x >> 6;
    const int lane = threadIdx.x & 63;
    const int q    = blockIdx.x * 4 + wid;
    const int b    = q >> 10;
    const int s    = q & 1023;

    __shared__ float xls[4][KNB][DFEAT];   // 32 KB, wave-local
    __shared__ float h1s[4][DFEAT];        // 1 KB, wave-local

    float w1r[64], w2ra[64], w2rb[64];
    {
        const float4* W1v = (const float4*)(W1 + (size_t)lane * 64);
        const float4* W2a = (const float4*)(W2 + (size_t)lane * 64);
        const float4* W2b = (const float4*)(W2 + (size_t)(lane + 64) * 64);
#pragma unroll
        for (int i = 0; i < 16; i++) {
            float4 v = W1v[i];
            w1r[4 * i] = v.x; w1r[4 * i + 1] = v.y; w1r[4 * i + 2] = v.z; w1r[4 * i + 3] = v.w;
            v = W2a[i];
            w2ra[4 * i] = v.x; w2ra[4 * i + 1] = v.y; w2ra[4 * i + 2] = v.z; w2ra[4 * i + 3] = v.w;
            v = W2b[i];
            w2rb[4 * i] = v.x; w2rb[4 * i + 1] = v.y; w2rb[4 * i + 2] = v.z; w2rb[4 * i + 3] = v.w;
        }
    }
    const float b1r  = b1[lane];
    const float b2ra = b2[lane];
    const float b2rb = b2[lane + 64];

    int gi = 0;
    if (lane < KNB) gi = grp[(size_t)q * KNB + lane];
    const float* fb = features + (size_t)b * NPTS * DFEAT;
    for (int k = 0; k < KNB; k++) {
        const int idxk = __shfl(gi, k);
        xls[wid][k][lane] = fb[(size_t)idxk * DFEAT + lane];
    }

    float m0 = 0.0f, m1 = 0.0f;   // relu outputs >= 0
    for (int k = 0; k < KNB; k++) {
        float acc = b1r;
        const float4* xk = (const float4*)xls[wid][k];
#pragma unroll
        for (int i = 0; i < 16; i++) {
            const float4 v = xk[i];
            acc = fmaf(v.x, w1r[4 * i], acc);
            acc = fmaf(v.y, w1r[4 * i + 1], acc);
            acc = fmaf(v.z, w1r[4 * i + 2], acc);
            acc = fmaf(v.w, w1r[4 * i + 3], acc);
        }
        h1s[wid][lane] = fmaxf(acc, 0.0f);
        float a0 = b2ra, a1 = b2rb;
        const float4* hv4 = (const float4*)h1s[wid];
#pragma unroll
        for (int i = 0; i < 16; i++) {
            const float4 v = hv4[i];
            a0 = fmaf(v.x, w2ra[4 * i], a0);
            a0 = fmaf(v.y, w2ra[4 * i + 1], a0);
            a0 = fmaf(v.z, w2ra[4 * i + 2], a0);
            a0 = fmaf(v.w, w2ra[4 * i + 3], a0);
            a1 = fmaf(v.x, w2rb[4 * i], a1);
            a1 = fmaf(v.y, w2rb[4 * i + 1], a1);
            a1 = fmaf(v.z, w2rb[4 * i + 2], a1);
            a1 = fmaf(v.w, w2rb[4 * i + 3], a1);
        }
        m0 = fmaxf(m0, fmaxf(a0, 0.0f));
        m1 = fmaxf(m1, fmaxf(a1, 0.0f));
    }

    out_pts[(size_t)b * 128 * NSAMP + (size_t)lane * NSAMP + s]        = m0;
    out_pts[(size_t)b * 128 * NSAMP + (size_t)(lane + 64) * NSAMP + s] = m1;
}

extern "C" void kernel_launch(void* const* d_in, const int* in_sizes, int n_in,
                              void* d_out, int out_size, void* d_ws, size_t ws_size,
                              hipStream_t stream) {
    const float* xyz      = (const float*)d_in[0];
    const float* features = (const float*)d_in[1];
    const float* W1       = (const float*)d_in[2];
    const float* b1       = (const float*)d_in[3];
    const float* W2       = (const float*)d_in[4];
    const float* b2       = (const float*)d_in[5];

    float* out_xyz = (float*)d_out;                                  // [B,3,S]
    float* out_pts = (float*)d_out + (size_t)BATCH * 3 * NSAMP;      // [B,128,S]

    int* grp = (int*)d_ws;                                           // [B,S,32]

    fps_kernel<<<BATCH, FPS_T, 0, stream>>>(xyz, out_xyz);
    ballq_kernel<<<BATCH * NSAMP / 4, 256, 0, stream>>>(xyz, out_xyz, grp);
    mlp_kernel<<<BATCH * NSAMP / 4, 256, 0, stream>>>(features, grp, W1, b1, W2, b2, out_pts);
}

// Round 7
// 808.093 us; speedup vs baseline: 1.6284x; 1.0843x over previous
//
#include <hip/hip_runtime.h>
#include <hip/hip_bf16.h>

#define BATCH 16
#define NPTS  4096
#define NSAMP 1024   // S = N * 0.25
#define KNB   32     // nsample
#define DFEAT 64

#define THREADS  256
#define FPS_PPT  (NPTS / THREADS)   // 16 points per thread
#define FPS_W    (THREADS / 64)     // 4 waves
#define NWBLK    240                // worker blocks
#define NWAVES   (NWBLK * FPS_W)    // 960 worker waves
#define NTASK    (BATCH * NSAMP)    // 16384 (b, sq) tasks
#define TAG_BASE 0xC0FFEE00u

// ---------------------------------------------------------------------------
// DPP wave64 max-reduce round on packed u64 key (key-only).
// Key = (f32_bits(value) << 32) | ~idx : max key == max value, ties -> min idx.
// ---------------------------------------------------------------------------
template <int CTRL, int RMASK>
__device__ __forceinline__ void dpp_round(unsigned long long& key) {
    const int klo = (int)(unsigned)key;
    const int khi = (int)(unsigned)(key >> 32);
    const int tlo = __builtin_amdgcn_update_dpp(klo, klo, CTRL, RMASK, 0xF, false);
    const int thi = __builtin_amdgcn_update_dpp(khi, khi, CTRL, RMASK, 0xF, false);
    const unsigned long long tk =
        ((unsigned long long)(unsigned)thi << 32) | (unsigned)tlo;
    if (tk > key) key = tk;
}

__device__ __forceinline__ void pub_store(unsigned long long* p, unsigned long long v) {
    __hip_atomic_store(p, v, __ATOMIC_RELAXED, __HIP_MEMORY_SCOPE_AGENT);
}
__device__ __forceinline__ unsigned long long pub_load(const unsigned long long* p) {
    return __hip_atomic_load(p, __ATOMIC_RELAXED, __HIP_MEMORY_SCOPE_AGENT);
}

// ---------------------------------------------------------------------------
// Fused kernel. Blocks 0..15: FPS (one batch each), publishing each centroid
// as 3 self-tagged u64 words. Blocks 16..255: workers — poll centroid, ball
// query + gather + MLP + maxpool for each (b, sq) task, sq-major order.
// All 256 blocks are co-resident (<=2 blocks/CU capacity) -> no deadlock.
// ---------------------------------------------------------------------------
__global__ __launch_bounds__(THREADS) void fused_kernel(
    const float* __restrict__ xyz, const float* __restrict__ features,
    const float* __restrict__ W1, const float* __restrict__ b1,
    const float* __restrict__ W2, const float* __restrict__ b2,
    float* __restrict__ out_xyz, float* __restrict__ out_pts,
    unsigned long long* __restrict__ pub) {

    __shared__ alignas(16) unsigned char smem[65536 + 12288 + 512];
    const int bid  = blockIdx.x;
    const int tid  = threadIdx.x;
    const int lane = tid & 63;
    const int wid  = tid >> 6;

    if (bid < BATCH) {
        // =================== FPS (identical math to R6) ====================
        float4* sc = (float4*)smem;                          // 64 KB coords
        float* stX = (float*)(smem + 65536);                 // 12 KB staging
        float* stY = stX + NSAMP;
        float* stZ = stY + NSAMP;
        unsigned long long* pw = (unsigned long long*)(smem + 65536 + 12288);

        float px[FPS_PPT], py[FPS_PPT], pz[FPS_PPT], md[FPS_PPT];
        const float* base = xyz + (size_t)bid * NPTS * 3;
#pragma unroll
        for (int j = 0; j < FPS_PPT; j++) {
            const int i = j * THREADS + tid;
            const float x = base[i * 3 + 0];
            const float y = base[i * 3 + 1];
            const float z = base[i * 3 + 2];
            sc[i] = make_float4(x, y, z, 0.0f);
            px[j] = x; py[j] = y; pz[j] = z;
            md[j] = 1e10f;
        }

        float cx = base[0], cy = base[1], cz = base[2];
        unsigned long long* pb = pub + (size_t)bid * NSAMP * 3;
        if (tid == 0) {
            stX[0] = cx; stY[0] = cy; stZ[0] = cz;
            pub_store(&pb[0], ((unsigned long long)__float_as_uint(cx) << 32) | (TAG_BASE + 0));
            pub_store(&pb[1], ((unsigned long long)__float_as_uint(cy) << 32) | (TAG_BASE + 0));
            pub_store(&pb[2], ((unsigned long long)__float_as_uint(cz) << 32) | (TAG_BASE + 0));
        }
        __syncthreads();

        for (int s = 1; s < NSAMP; s++) {
            float best = -1.0f;
            int   bj   = 0;
#pragma unroll
            for (int j = 0; j < FPS_PPT; j++) {
                const float dx = px[j] - cx;
                const float dy = py[j] - cy;
                const float dz = pz[j] - cz;
                const float d = __fadd_rn(__fadd_rn(__fmul_rn(dx, dx), __fmul_rn(dy, dy)),
                                          __fmul_rn(dz, dz));
                const float m = fminf(md[j], d);
                md[j] = m;
                if (m > best) { best = m; bj = j; }
            }
            const int bi = (bj << 8) | tid;
            unsigned long long key =
                ((unsigned long long)__float_as_uint(best) << 32) | (unsigned)(~bi);
            dpp_round<0x111, 0xF>(key);
            dpp_round<0x112, 0xF>(key);
            dpp_round<0x114, 0xF>(key);
            dpp_round<0x118, 0xF>(key);
            dpp_round<0x142, 0xA>(key);
            dpp_round<0x143, 0xC>(key);

            const int par = s & 1;
            if (lane == 63) pw[par * FPS_W + wid] = key;
            __syncthreads();
            const ulong2 p01 = *(const ulong2*)&pw[par * FPS_W + 0];
            const ulong2 p23 = *(const ulong2*)&pw[par * FPS_W + 2];
            unsigned long long bk = p01.x;
            if (p01.y > bk) bk = p01.y;
            if (p23.x > bk) bk = p23.x;
            if (p23.y > bk) bk = p23.y;
            const int bix = (int)(~(unsigned)bk);

            const float4 c = sc[bix];
            cx = c.x; cy = c.y; cz = c.z;
            if (tid == 0) {
                stX[s] = cx; stY[s] = cy; stZ[s] = cz;
                pub_store(&pb[3 * s + 0], ((unsigned long long)__float_as_uint(cx) << 32) | (TAG_BASE + s));
                pub_store(&pb[3 * s + 1], ((unsigned long long)__float_as_uint(cy) << 32) | (TAG_BASE + s));
                pub_store(&pb[3 * s + 2], ((unsigned long long)__float_as_uint(cz) << 32) | (TAG_BASE + s));
            }
        }

        __syncthreads();
        float* ob = out_xyz + (size_t)bid * 3 * NSAMP;
        for (int i = tid; i < NSAMP; i += THREADS) {
            ob[0 * NSAMP + i] = stX[i];
            ob[1 * NSAMP + i] = stY[i];
            ob[2 * NSAMP + i] = stZ[i];
        }
    } else {
        // ========================== WORKER =================================
        float (*xls)[KNB][DFEAT] = (float (*)[KNB][DFEAT])smem;        // 32 KB
        float (*h1s)[DFEAT]      = (float (*)[DFEAT])(smem + 32768);   // 1 KB
        int   (*gl)[KNB]         = (int (*)[KNB])(smem + 32768 + 1024);// 512 B

        // weights -> registers (once per wave)
        float w1r[64], w2ra[64], w2rb[64];
        {
            const float4* W1v = (const float4*)(W1 + (size_t)lane * 64);
            const float4* W2a = (const float4*)(W2 + (size_t)lane * 64);
            const float4* W2b = (const float4*)(W2 + (size_t)(lane + 64) * 64);
#pragma unroll
            for (int i = 0; i < 16; i++) {
                float4 v = W1v[i];
                w1r[4 * i] = v.x; w1r[4 * i + 1] = v.y; w1r[4 * i + 2] = v.z; w1r[4 * i + 3] = v.w;
                v = W2a[i];
                w2ra[4 * i] = v.x; w2ra[4 * i + 1] = v.y; w2ra[4 * i + 2] = v.z; w2ra[4 * i + 3] = v.w;
                v = W2b[i];
                w2rb[4 * i] = v.x; w2rb[4 * i + 1] = v.y; w2rb[4 * i + 2] = v.z; w2rb[4 * i + 3] = v.w;
            }
        }
        const float b1r  = b1[lane];
        const float b2ra = b2[lane];
        const float b2rb = b2[lane + 64];

        const int gwave = (bid - BATCH) * FPS_W + wid;
        for (int t = gwave; t < NTASK; t += NWAVES) {
            const int sq = t >> 4;    // sq-major: waves sweep s together
            const int b  = t & 15;

            // ---- poll centroid (3 self-tagged words; no fences needed) ----
            const unsigned long long* pp = pub + ((size_t)b * NSAMP + sq) * 3;
            const unsigned exp_tag = TAG_BASE + sq;
            unsigned long long w0, w1, w2;
            for (;;) {
                w0 = pub_load(&pp[0]);
                w1 = pub_load(&pp[1]);
                w2 = pub_load(&pp[2]);
                if ((unsigned)w0 == exp_tag && (unsigned)w1 == exp_tag &&
                    (unsigned)w2 == exp_tag) break;
                __builtin_amdgcn_s_sleep(2);
            }
            const float cx = __uint_as_float((unsigned)(w0 >> 32));
            const float cy = __uint_as_float((unsigned)(w1 >> 32));
            const float cz = __uint_as_float((unsigned)(w2 >> 32));

            // ---- ball query into wave-local LDS slice ----
            const float* base = xyz + (size_t)b * NPTS * 3;
            const float r2 = 0.04f;
            int cnt = 0;
            int firstCand = 0x7fffffff;
            for (int bp = 0; bp < NPTS && cnt < KNB; bp += 64) {
                const int p = bp + lane;
                const float dx = base[p * 3 + 0] - cx;
                const float dy = base[p * 3 + 1] - cy;
                const float dz = base[p * 3 + 2] - cz;
                const float d = __fadd_rn(__fadd_rn(__fmul_rn(dx, dx), __fmul_rn(dy, dy)),
                                          __fmul_rn(dz, dz));
                const bool ok = !(d > r2);
                const unsigned long long m = __ballot(ok);
                const int rank = cnt + (int)__popcll(m & ((1ull << lane) - 1ull));
                if (ok && rank < KNB) gl[wid][rank] = p;
                if (ok && rank == 0) firstCand = p;
                cnt += (int)__popcll(m);
            }
            const int found = cnt < KNB ? cnt : KNB;
            if (found < KNB) {
#pragma unroll
                for (int off = 32; off > 0; off >>= 1) {
                    const int o = __shfl_xor(firstCand, off);
                    firstCand = o < firstCand ? o : firstCand;
                }
                for (int r = found + lane; r < KNB; r += 64) gl[wid][r] = firstCand;
            }
            int gi = 0;
            if (lane < KNB) gi = gl[wid][lane];

            // ---- gather 32 neighbor feature rows into LDS ----
            const float* fb = features + (size_t)b * NPTS * DFEAT;
            for (int k = 0; k < KNB; k++) {
                const int idxk = __shfl(gi, k);
                xls[wid][k][lane] = fb[(size_t)idxk * DFEAT + lane];
            }

            // ---- MLP + maxpool ----
            float m0 = 0.0f, m1 = 0.0f;
            for (int k = 0; k < KNB; k++) {
                float acc = b1r;
                const float4* xk = (const float4*)xls[wid][k];
#pragma unroll
                for (int i = 0; i < 16; i++) {
                    const float4 v = xk[i];
                    acc = fmaf(v.x, w1r[4 * i], acc);
                    acc = fmaf(v.y, w1r[4 * i + 1], acc);
                    acc = fmaf(v.z, w1r[4 * i + 2], acc);
                    acc = fmaf(v.w, w1r[4 * i + 3], acc);
                }
                h1s[wid][lane] = fmaxf(acc, 0.0f);
                float a0 = b2ra, a1 = b2rb;
                const float4* hv4 = (const float4*)h1s[wid];
#pragma unroll
                for (int i = 0; i < 16; i++) {
                    const float4 v = hv4[i];
                    a0 = fmaf(v.x, w2ra[4 * i], a0);
                    a0 = fmaf(v.y, w2ra[4 * i + 1], a0);
                    a0 = fmaf(v.z, w2ra[4 * i + 2], a0);
                    a0 = fmaf(v.w, w2ra[4 * i + 3], a0);
                    a1 = fmaf(v.x, w2rb[4 * i], a1);
                    a1 = fmaf(v.y, w2rb[4 * i + 1], a1);
                    a1 = fmaf(v.z, w2rb[4 * i + 2], a1);
                    a1 = fmaf(v.w, w2rb[4 * i + 3], a1);
                }
                m0 = fmaxf(m0, fmaxf(a0, 0.0f));
                m1 = fmaxf(m1, fmaxf(a1, 0.0f));
            }

            out_pts[(size_t)b * 128 * NSAMP + (size_t)lane * NSAMP + sq]        = m0;
            out_pts[(size_t)b * 128 * NSAMP + (size_t)(lane + 64) * NSAMP + sq] = m1;
        }
    }
}

extern "C" void kernel_launch(void* const* d_in, const int* in_sizes, int n_in,
                              void* d_out, int out_size, void* d_ws, size_t ws_size,
                              hipStream_t stream) {
    const float* xyz      = (const float*)d_in[0];
    const float* features = (const float*)d_in[1];
    const float* W1       = (const float*)d_in[2];
    const float* b1       = (const float*)d_in[3];
    const float* W2       = (const float*)d_in[4];
    const float* b2       = (const float*)d_in[5];

    float* out_xyz = (float*)d_out;                                  // [B,3,S]
    float* out_pts = (float*)d_out + (size_t)BATCH * 3 * NSAMP;      // [B,128,S]

    unsigned long long* pub = (unsigned long long*)d_ws;             // [B,S,3]

    fused_kernel<<<BATCH + NWBLK, THREADS, 0, stream>>>(
        xyz, features, W1, b1, W2, b2, out_xyz, out_pts, pub);
}

// Round 8
// 807.089 us; speedup vs baseline: 1.6304x; 1.0012x over previous
//
#include <hip/hip_runtime.h>
#include <hip/hip_bf16.h>

#define BATCH 16
#define NPTS  4096
#define NSAMP 1024   // S = N * 0.25
#define KNB   32     // nsample
#define DFEAT 64

#define THREADS  256
#define FPS_PPT  (NPTS / THREADS)   // 16 points per thread
#define FPS_W    (THREADS / 64)     // 4 waves
#define NWBLK    240                // worker blocks
#define NWAVES   (NWBLK * FPS_W)    // 960 worker waves
#define NTASK    (BATCH * NSAMP)    // 16384 (b, sq) tasks
#define TAG_BASE 0xC0FFEE00u

// ---------------------------------------------------------------------------
// DPP wave64 max-reduce round on packed u64 key (key-only).
// Key = (f32_bits(value) << 32) | ~idx : max key == max value, ties -> min idx.
// ---------------------------------------------------------------------------
template <int CTRL, int RMASK>
__device__ __forceinline__ void dpp_round(unsigned long long& key) {
    const int klo = (int)(unsigned)key;
    const int khi = (int)(unsigned)(key >> 32);
    const int tlo = __builtin_amdgcn_update_dpp(klo, klo, CTRL, RMASK, 0xF, false);
    const int thi = __builtin_amdgcn_update_dpp(khi, khi, CTRL, RMASK, 0xF, false);
    const unsigned long long tk =
        ((unsigned long long)(unsigned)thi << 32) | (unsigned)tlo;
    if (tk > key) key = tk;
}

__device__ __forceinline__ void pub_store(unsigned long long* p, unsigned long long v) {
    __hip_atomic_store(p, v, __ATOMIC_RELAXED, __HIP_MEMORY_SCOPE_AGENT);
}
__device__ __forceinline__ unsigned long long pub_load(const unsigned long long* p) {
    return __hip_atomic_load(p, __ATOMIC_RELAXED, __HIP_MEMORY_SCOPE_AGENT);
}

// Block barrier that waits only on LDS ops (lgkmcnt), NOT on outstanding
// global stores (vmcnt) -- lets the publish stores stay in flight across
// the serial loop's barrier instead of draining ~500 cyc/step.
__device__ __forceinline__ void barrier_lds_only() {
    asm volatile("s_waitcnt lgkmcnt(0)" ::: "memory");
    __builtin_amdgcn_s_barrier();
}

// ---------------------------------------------------------------------------
// Fused kernel. Blocks 0..15: FPS (one batch each), publishing each centroid
// as 3 self-tagged u64 words. Blocks 16..255: workers — poll centroid, ball
// query + gather + MLP + maxpool for each (b, sq) task, sq-major order.
// All 256 blocks are co-resident (256 blocks / 256 CUs) -> no deadlock.
// ---------------------------------------------------------------------------
__global__ __launch_bounds__(THREADS) void fused_kernel(
    const float* __restrict__ xyz, const float* __restrict__ features,
    const float* __restrict__ W1, const float* __restrict__ b1,
    const float* __restrict__ W2, const float* __restrict__ b2,
    float* __restrict__ out_xyz, float* __restrict__ out_pts,
    unsigned long long* __restrict__ pub) {

    __shared__ alignas(16) unsigned char smem[65536 + 12288 + 512];
    const int bid  = blockIdx.x;
    const int tid  = threadIdx.x;
    const int lane = tid & 63;
    const int wid  = tid >> 6;

    if (bid < BATCH) {
        // =================== FPS (identical math to R6) ====================
        float4* sc = (float4*)smem;                          // 64 KB coords
        float* stX = (float*)(smem + 65536);                 // 12 KB staging
        float* stY = stX + NSAMP;
        float* stZ = stY + NSAMP;
        unsigned long long* pw = (unsigned long long*)(smem + 65536 + 12288);

        float px[FPS_PPT], py[FPS_PPT], pz[FPS_PPT], md[FPS_PPT];
        const float* base = xyz + (size_t)bid * NPTS * 3;
#pragma unroll
        for (int j = 0; j < FPS_PPT; j++) {
            const int i = j * THREADS + tid;
            const float x = base[i * 3 + 0];
            const float y = base[i * 3 + 1];
            const float z = base[i * 3 + 2];
            sc[i] = make_float4(x, y, z, 0.0f);
            px[j] = x; py[j] = y; pz[j] = z;
            md[j] = 1e10f;
        }

        float cx = base[0], cy = base[1], cz = base[2];
        unsigned long long* pb = pub + (size_t)bid * NSAMP * 3;
        if (tid == 0) {
            stX[0] = cx; stY[0] = cy; stZ[0] = cz;
            pub_store(&pb[0], ((unsigned long long)__float_as_uint(cx) << 32) | (TAG_BASE + 0));
            pub_store(&pb[1], ((unsigned long long)__float_as_uint(cy) << 32) | (TAG_BASE + 0));
            pub_store(&pb[2], ((unsigned long long)__float_as_uint(cz) << 32) | (TAG_BASE + 0));
        }
        __syncthreads();

        for (int s = 1; s < NSAMP; s++) {
            float best = -1.0f;
            int   bj   = 0;
#pragma unroll
            for (int j = 0; j < FPS_PPT; j++) {
                const float dx = px[j] - cx;
                const float dy = py[j] - cy;
                const float dz = pz[j] - cz;
                const float d = __fadd_rn(__fadd_rn(__fmul_rn(dx, dx), __fmul_rn(dy, dy)),
                                          __fmul_rn(dz, dz));
                const float m = fminf(md[j], d);
                md[j] = m;
                if (m > best) { best = m; bj = j; }
            }
            const int bi = (bj << 8) | tid;
            unsigned long long key =
                ((unsigned long long)__float_as_uint(best) << 32) | (unsigned)(~bi);
            dpp_round<0x111, 0xF>(key);
            dpp_round<0x112, 0xF>(key);
            dpp_round<0x114, 0xF>(key);
            dpp_round<0x118, 0xF>(key);
            dpp_round<0x142, 0xA>(key);
            dpp_round<0x143, 0xC>(key);

            const int par = s & 1;
            if (lane == 63) pw[par * FPS_W + wid] = key;
            barrier_lds_only();           // waits lgkmcnt only; pub stores fly
            const ulong2 p01 = *(const ulong2*)&pw[par * FPS_W + 0];
            const ulong2 p23 = *(const ulong2*)&pw[par * FPS_W + 2];
            unsigned long long bk = p01.x;
            if (p01.y > bk) bk = p01.y;
            if (p23.x > bk) bk = p23.x;
            if (p23.y > bk) bk = p23.y;
            const int bix = (int)(~(unsigned)bk);

            const float4 c = sc[bix];
            cx = c.x; cy = c.y; cz = c.z;
            if (tid == 0) {
                stX[s] = cx; stY[s] = cy; stZ[s] = cz;
                pub_store(&pb[3 * s + 0], ((unsigned long long)__float_as_uint(cx) << 32) | (TAG_BASE + s));
                pub_store(&pb[3 * s + 1], ((unsigned long long)__float_as_uint(cy) << 32) | (TAG_BASE + s));
                pub_store(&pb[3 * s + 2], ((unsigned long long)__float_as_uint(cz) << 32) | (TAG_BASE + s));
            }
        }

        __syncthreads();
        float* ob = out_xyz + (size_t)bid * 3 * NSAMP;
        for (int i = tid; i < NSAMP; i += THREADS) {
            ob[0 * NSAMP + i] = stX[i];
            ob[1 * NSAMP + i] = stY[i];
            ob[2 * NSAMP + i] = stZ[i];
        }
    } else {
        // ========================== WORKER =================================
        float (*xls)[KNB][DFEAT] = (float (*)[KNB][DFEAT])smem;        // 32 KB
        float (*h1s)[DFEAT]      = (float (*)[DFEAT])(smem + 32768);   // 1 KB
        int   (*gl)[KNB]         = (int (*)[KNB])(smem + 32768 + 1024);// 512 B

        // weights -> registers (once per wave)
        float w1r[64], w2ra[64], w2rb[64];
        {
            const float4* W1v = (const float4*)(W1 + (size_t)lane * 64);
            const float4* W2a = (const float4*)(W2 + (size_t)lane * 64);
            const float4* W2b = (const float4*)(W2 + (size_t)(lane + 64) * 64);
#pragma unroll
            for (int i = 0; i < 16; i++) {
                float4 v = W1v[i];
                w1r[4 * i] = v.x; w1r[4 * i + 1] = v.y; w1r[4 * i + 2] = v.z; w1r[4 * i + 3] = v.w;
                v = W2a[i];
                w2ra[4 * i] = v.x; w2ra[4 * i + 1] = v.y; w2ra[4 * i + 2] = v.z; w2ra[4 * i + 3] = v.w;
                v = W2b[i];
                w2rb[4 * i] = v.x; w2rb[4 * i + 1] = v.y; w2rb[4 * i + 2] = v.z; w2rb[4 * i + 3] = v.w;
            }
        }
        const float b1r  = b1[lane];
        const float b2ra = b2[lane];
        const float b2rb = b2[lane + 64];

        const int gwave = (bid - BATCH) * FPS_W + wid;
        for (int t = gwave; t < NTASK; t += NWAVES) {
            const int sq = t >> 4;    // sq-major: waves sweep s together
            const int b  = t & 15;

            // ---- poll centroid (3 self-tagged words; no fences needed) ----
            const unsigned long long* pp = pub + ((size_t)b * NSAMP + sq) * 3;
            const unsigned exp_tag = TAG_BASE + sq;
            unsigned long long w0, w1, w2;
            for (;;) {
                w0 = pub_load(&pp[0]);
                w1 = pub_load(&pp[1]);
                w2 = pub_load(&pp[2]);
                if ((unsigned)w0 == exp_tag && (unsigned)w1 == exp_tag &&
                    (unsigned)w2 == exp_tag) break;
                __builtin_amdgcn_s_sleep(2);
            }
            const float cx = __uint_as_float((unsigned)(w0 >> 32));
            const float cy = __uint_as_float((unsigned)(w1 >> 32));
            const float cz = __uint_as_float((unsigned)(w2 >> 32));

            // ---- ball query into wave-local LDS slice ----
            const float* base = xyz + (size_t)b * NPTS * 3;
            const float r2 = 0.04f;
            int cnt = 0;
            int firstCand = 0x7fffffff;
            for (int bp = 0; bp < NPTS && cnt < KNB; bp += 64) {
                const int p = bp + lane;
                const float dx = base[p * 3 + 0] - cx;
                const float dy = base[p * 3 + 1] - cy;
                const float dz = base[p * 3 + 2] - cz;
                const float d = __fadd_rn(__fadd_rn(__fmul_rn(dx, dx), __fmul_rn(dy, dy)),
                                          __fmul_rn(dz, dz));
                const bool ok = !(d > r2);
                const unsigned long long m = __ballot(ok);
                const int rank = cnt + (int)__popcll(m & ((1ull << lane) - 1ull));
                if (ok && rank < KNB) gl[wid][rank] = p;
                if (ok && rank == 0) firstCand = p;
                cnt += (int)__popcll(m);
            }
            const int found = cnt < KNB ? cnt : KNB;
            if (found < KNB) {
#pragma unroll
                for (int off = 32; off > 0; off >>= 1) {
                    const int o = __shfl_xor(firstCand, off);
                    firstCand = o < firstCand ? o : firstCand;
                }
                for (int r = found + lane; r < KNB; r += 64) gl[wid][r] = firstCand;
            }
            int gi = 0;
            if (lane < KNB) gi = gl[wid][lane];

            // ---- gather 32 neighbor feature rows into LDS ----
            const float* fb = features + (size_t)b * NPTS * DFEAT;
            for (int k = 0; k < KNB; k++) {
                const int idxk = __shfl(gi, k);
                xls[wid][k][lane] = fb[(size_t)idxk * DFEAT + lane];
            }

            // ---- MLP + maxpool ----
            float m0 = 0.0f, m1 = 0.0f;
            for (int k = 0; k < KNB; k++) {
                float acc = b1r;
                const float4* xk = (const float4*)xls[wid][k];
#pragma unroll
                for (int i = 0; i < 16; i++) {
                    const float4 v = xk[i];
                    acc = fmaf(v.x, w1r[4 * i], acc);
                    acc = fmaf(v.y, w1r[4 * i + 1], acc);
                    acc = fmaf(v.z, w1r[4 * i + 2], acc);
                    acc = fmaf(v.w, w1r[4 * i + 3], acc);
                }
                h1s[wid][lane] = fmaxf(acc, 0.0f);
                float a0 = b2ra, a1 = b2rb;
                const float4* hv4 = (const float4*)h1s[wid];
#pragma unroll
                for (int i = 0; i < 16; i++) {
                    const float4 v = hv4[i];
                    a0 = fmaf(v.x, w2ra[4 * i], a0);
                    a0 = fmaf(v.y, w2ra[4 * i + 1], a0);
                    a0 = fmaf(v.z, w2ra[4 * i + 2], a0);
                    a0 = fmaf(v.w, w2ra[4 * i + 3], a0);
                    a1 = fmaf(v.x, w2rb[4 * i], a1);
                    a1 = fmaf(v.y, w2rb[4 * i + 1], a1);
                    a1 = fmaf(v.z, w2rb[4 * i + 2], a1);
                    a1 = fmaf(v.w, w2rb[4 * i + 3], a1);
                }
                m0 = fmaxf(m0, fmaxf(a0, 0.0f));
                m1 = fmaxf(m1, fmaxf(a1, 0.0f));
            }

            out_pts[(size_t)b * 128 * NSAMP + (size_t)lane * NSAMP + sq]        = m0;
            out_pts[(size_t)b * 128 * NSAMP + (size_t)(lane + 64) * NSAMP + sq] = m1;
        }
    }
}

extern "C" void kernel_launch(void* const* d_in, const int* in_sizes, int n_in,
                              void* d_out, int out_size, void* d_ws, size_t ws_size,
                              hipStream_t stream) {
    const float* xyz      = (const float*)d_in[0];
    const float* features = (const float*)d_in[1];
    const float* W1       = (const float*)d_in[2];
    const float* b1       = (const float*)d_in[3];
    const float* W2       = (const float*)d_in[4];
    const float* b2       = (const float*)d_in[5];

    float* out_xyz = (float*)d_out;                                  // [B,3,S]
    float* out_pts = (float*)d_out + (size_t)BATCH * 3 * NSAMP;      // [B,128,S]

    unsigned long long* pub = (unsigned long long*)d_ws;             // [B,S,3]

    fused_kernel<<<BATCH + NWBLK, THREADS, 0, stream>>>(
        xyz, features, W1, b1, W2, b2, out_xyz, out_pts, pub);
}

// Round 9
// 680.856 us; speedup vs baseline: 1.9327x; 1.1854x over previous
//
#include <hip/hip_runtime.h>
#include <hip/hip_bf16.h>

#define BATCH 16
#define NPTS  4096
#define NSAMP 1024   // S = N * 0.25
#define KNB   32     // nsample
#define DFEAT 64

#define THREADS  512
#define FPS_PPT  (NPTS / THREADS)   // 8 points per thread
#define NWV      (THREADS / 64)     // 8 waves per block
#define NWBLK    240                // worker blocks
#define NWAVES   (NWBLK * NWV)      // 1920 worker waves
#define NTASK    (BATCH * NSAMP)    // 16384 (b, sq) tasks
#define TAG_BASE 0xC0FFEE00u

// ---------------------------------------------------------------------------
// DPP wave64 max-reduce round on packed u64 key (key-only).
// Key = (f32_bits(value) << 32) | ~idx : max key == max value, ties -> min idx.
// ---------------------------------------------------------------------------
template <int CTRL, int RMASK>
__device__ __forceinline__ void dpp_round(unsigned long long& key) {
    const int klo = (int)(unsigned)key;
    const int khi = (int)(unsigned)(key >> 32);
    const int tlo = __builtin_amdgcn_update_dpp(klo, klo, CTRL, RMASK, 0xF, false);
    const int thi = __builtin_amdgcn_update_dpp(khi, khi, CTRL, RMASK, 0xF, false);
    const unsigned long long tk =
        ((unsigned long long)(unsigned)thi << 32) | (unsigned)tlo;
    if (tk > key) key = tk;
}

__device__ __forceinline__ void pub_store(unsigned long long* p, unsigned long long v) {
    __hip_atomic_store(p, v, __ATOMIC_RELAXED, __HIP_MEMORY_SCOPE_AGENT);
}
__device__ __forceinline__ unsigned long long pub_load(const unsigned long long* p) {
    return __hip_atomic_load(p, __ATOMIC_RELAXED, __HIP_MEMORY_SCOPE_AGENT);
}

// Barrier waiting only on LDS ops (publish stores stay in flight).
__device__ __forceinline__ void barrier_lds_only() {
    asm volatile("s_waitcnt lgkmcnt(0)" ::: "memory");
    __builtin_amdgcn_s_barrier();
}

// ---------------------------------------------------------------------------
// Fused kernel, 512 threads/block. Blocks 0..15: FPS (one batch each),
// publishing each centroid as 3 self-tagged u64 words. Blocks 16..255:
// workers (8 waves each) — poll centroid, ball query + gather + MLP +
// maxpool per (b, sq) task, sq-major order. 256 blocks co-resident.
// ---------------------------------------------------------------------------
__global__ __launch_bounds__(THREADS) void fused_kernel(
    const float* __restrict__ xyz, const float* __restrict__ features,
    const float* __restrict__ W1, const float* __restrict__ b1,
    const float* __restrict__ W2, const float* __restrict__ b2,
    float* __restrict__ out_xyz, float* __restrict__ out_pts,
    unsigned long long* __restrict__ pub) {

    __shared__ alignas(16) unsigned char smem[65536 + 12288 + 512];
    const int bid  = blockIdx.x;
    const int tid  = threadIdx.x;
    const int lane = tid & 63;
    const int wid  = tid >> 6;

    if (bid < BATCH) {
        // =================== FPS (identical math, 8 waves) =================
        float4* sc = (float4*)smem;                          // 64 KB coords
        float* stX = (float*)(smem + 65536);                 // 12 KB staging
        float* stY = stX + NSAMP;
        float* stZ = stY + NSAMP;
        unsigned long long* pw = (unsigned long long*)(smem + 65536 + 12288);

        float px[FPS_PPT], py[FPS_PPT], pz[FPS_PPT], md[FPS_PPT];
        const float* base = xyz + (size_t)bid * NPTS * 3;
#pragma unroll
        for (int j = 0; j < FPS_PPT; j++) {
            const int i = j * THREADS + tid;
            const float x = base[i * 3 + 0];
            const float y = base[i * 3 + 1];
            const float z = base[i * 3 + 2];
            sc[i] = make_float4(x, y, z, 0.0f);
            px[j] = x; py[j] = y; pz[j] = z;
            md[j] = 1e10f;
        }

        float cx = base[0], cy = base[1], cz = base[2];
        unsigned long long* pb = pub + (size_t)bid * NSAMP * 3;
        if (tid == 0) {
            stX[0] = cx; stY[0] = cy; stZ[0] = cz;
            pub_store(&pb[0], ((unsigned long long)__float_as_uint(cx) << 32) | (TAG_BASE + 0));
            pub_store(&pb[1], ((unsigned long long)__float_as_uint(cy) << 32) | (TAG_BASE + 0));
            pub_store(&pb[2], ((unsigned long long)__float_as_uint(cz) << 32) | (TAG_BASE + 0));
        }
        __syncthreads();

        for (int s = 1; s < NSAMP; s++) {
            float best = -1.0f;
            int   bj   = 0;
#pragma unroll
            for (int j = 0; j < FPS_PPT; j++) {
                const float dx = px[j] - cx;
                const float dy = py[j] - cy;
                const float dz = pz[j] - cz;
                const float d = __fadd_rn(__fadd_rn(__fmul_rn(dx, dx), __fmul_rn(dy, dy)),
                                          __fmul_rn(dz, dz));
                const float m = fminf(md[j], d);
                md[j] = m;
                if (m > best) { best = m; bj = j; }
            }
            const int bi = (bj << 9) | tid;    // j*512 + tid (disjoint bits)
            unsigned long long key =
                ((unsigned long long)__float_as_uint(best) << 32) | (unsigned)(~bi);
            dpp_round<0x111, 0xF>(key);
            dpp_round<0x112, 0xF>(key);
            dpp_round<0x114, 0xF>(key);
            dpp_round<0x118, 0xF>(key);
            dpp_round<0x142, 0xA>(key);
            dpp_round<0x143, 0xC>(key);

            const int par = s & 1;
            if (lane == 63) pw[par * NWV + wid] = key;
            barrier_lds_only();
            const ulong2 p01 = *(const ulong2*)&pw[par * NWV + 0];
            const ulong2 p23 = *(const ulong2*)&pw[par * NWV + 2];
            const ulong2 p45 = *(const ulong2*)&pw[par * NWV + 4];
            const ulong2 p67 = *(const ulong2*)&pw[par * NWV + 6];
            unsigned long long bk = p01.x;
            if (p01.y > bk) bk = p01.y;
            if (p23.x > bk) bk = p23.x;
            if (p23.y > bk) bk = p23.y;
            if (p45.x > bk) bk = p45.x;
            if (p45.y > bk) bk = p45.y;
            if (p67.x > bk) bk = p67.x;
            if (p67.y > bk) bk = p67.y;
            const int bix = (int)(~(unsigned)bk);

            const float4 c = sc[bix];
            cx = c.x; cy = c.y; cz = c.z;
            if (tid == 0) {
                stX[s] = cx; stY[s] = cy; stZ[s] = cz;
                pub_store(&pb[3 * s + 0], ((unsigned long long)__float_as_uint(cx) << 32) | (TAG_BASE + s));
                pub_store(&pb[3 * s + 1], ((unsigned long long)__float_as_uint(cy) << 32) | (TAG_BASE + s));
                pub_store(&pb[3 * s + 2], ((unsigned long long)__float_as_uint(cz) << 32) | (TAG_BASE + s));
            }
        }

        __syncthreads();
        float* ob = out_xyz + (size_t)bid * 3 * NSAMP;
        for (int i = tid; i < NSAMP; i += THREADS) {
            ob[0 * NSAMP + i] = stX[i];
            ob[1 * NSAMP + i] = stY[i];
            ob[2 * NSAMP + i] = stZ[i];
        }
    } else {
        // ========================== WORKER (8 waves) =======================
        float (*xls)[KNB][DFEAT] = (float (*)[KNB][DFEAT])smem;          // 64 KB
        float (*h1s)[DFEAT]      = (float (*)[DFEAT])(smem + 65536);     // 2 KB
        int   (*gl)[KNB]         = (int (*)[KNB])(smem + 65536 + 2048);  // 1 KB

        // weights -> registers (once per wave)
        float w1r[64], w2ra[64], w2rb[64];
        {
            const float4* W1v = (const float4*)(W1 + (size_t)lane * 64);
            const float4* W2a = (const float4*)(W2 + (size_t)lane * 64);
            const float4* W2b = (const float4*)(W2 + (size_t)(lane + 64) * 64);
#pragma unroll
            for (int i = 0; i < 16; i++) {
                float4 v = W1v[i];
                w1r[4 * i] = v.x; w1r[4 * i + 1] = v.y; w1r[4 * i + 2] = v.z; w1r[4 * i + 3] = v.w;
                v = W2a[i];
                w2ra[4 * i] = v.x; w2ra[4 * i + 1] = v.y; w2ra[4 * i + 2] = v.z; w2ra[4 * i + 3] = v.w;
                v = W2b[i];
                w2rb[4 * i] = v.x; w2rb[4 * i + 1] = v.y; w2rb[4 * i + 2] = v.z; w2rb[4 * i + 3] = v.w;
            }
        }
        const float b1r  = b1[lane];
        const float b2ra = b2[lane];
        const float b2rb = b2[lane + 64];

        const int gwave = (bid - BATCH) * NWV + wid;
        for (int t = gwave; t < NTASK; t += NWAVES) {
            const int sq = t >> 4;    // sq-major: waves sweep s together
            const int b  = t & 15;

            // ---- poll centroid (3 self-tagged words; no fences needed) ----
            const unsigned long long* pp = pub + ((size_t)b * NSAMP + sq) * 3;
            const unsigned exp_tag = TAG_BASE + sq;
            unsigned long long w0, w1, w2;
            for (;;) {
                w0 = pub_load(&pp[0]);
                w1 = pub_load(&pp[1]);
                w2 = pub_load(&pp[2]);
                if ((unsigned)w0 == exp_tag && (unsigned)w1 == exp_tag &&
                    (unsigned)w2 == exp_tag) break;
                __builtin_amdgcn_s_sleep(2);
            }
            const float cx = __uint_as_float((unsigned)(w0 >> 32));
            const float cy = __uint_as_float((unsigned)(w1 >> 32));
            const float cz = __uint_as_float((unsigned)(w2 >> 32));

            // ---- ball query into wave-local LDS slice ----
            const float* base = xyz + (size_t)b * NPTS * 3;
            const float r2 = 0.04f;
            int cnt = 0;
            int firstCand = 0x7fffffff;
            for (int bp = 0; bp < NPTS && cnt < KNB; bp += 64) {
                const int p = bp + lane;
                const float dx = base[p * 3 + 0] - cx;
                const float dy = base[p * 3 + 1] - cy;
                const float dz = base[p * 3 + 2] - cz;
                const float d = __fadd_rn(__fadd_rn(__fmul_rn(dx, dx), __fmul_rn(dy, dy)),
                                          __fmul_rn(dz, dz));
                const bool ok = !(d > r2);
                const unsigned long long m = __ballot(ok);
                const int rank = cnt + (int)__popcll(m & ((1ull << lane) - 1ull));
                if (ok && rank < KNB) gl[wid][rank] = p;
                if (ok && rank == 0) firstCand = p;
                cnt += (int)__popcll(m);
            }
            const int found = cnt < KNB ? cnt : KNB;
            if (found < KNB) {
#pragma unroll
                for (int off = 32; off > 0; off >>= 1) {
                    const int o = __shfl_xor(firstCand, off);
                    firstCand = o < firstCand ? o : firstCand;
                }
                for (int r = found + lane; r < KNB; r += 64) gl[wid][r] = firstCand;
            }
            int gi = 0;
            if (lane < KNB) gi = gl[wid][lane];

            // ---- gather 32 neighbor feature rows into LDS ----
            const float* fb = features + (size_t)b * NPTS * DFEAT;
            for (int k = 0; k < KNB; k++) {
                const int idxk = __shfl(gi, k);
                xls[wid][k][lane] = fb[(size_t)idxk * DFEAT + lane];
            }

            // ---- MLP + maxpool ----
            float m0 = 0.0f, m1 = 0.0f;
            for (int k = 0; k < KNB; k++) {
                float acc = b1r;
                const float4* xk = (const float4*)xls[wid][k];
#pragma unroll
                for (int i = 0; i < 16; i++) {
                    const float4 v = xk[i];
                    acc = fmaf(v.x, w1r[4 * i], acc);
                    acc = fmaf(v.y, w1r[4 * i + 1], acc);
                    acc = fmaf(v.z, w1r[4 * i + 2], acc);
                    acc = fmaf(v.w, w1r[4 * i + 3], acc);
                }
                h1s[wid][lane] = fmaxf(acc, 0.0f);
                float a0 = b2ra, a1 = b2rb;
                const float4* hv4 = (const float4*)h1s[wid];
#pragma unroll
                for (int i = 0; i < 16; i++) {
                    const float4 v = hv4[i];
                    a0 = fmaf(v.x, w2ra[4 * i], a0);
                    a0 = fmaf(v.y, w2ra[4 * i + 1], a0);
                    a0 = fmaf(v.z, w2ra[4 * i + 2], a0);
                    a0 = fmaf(v.w, w2ra[4 * i + 3], a0);
                    a1 = fmaf(v.x, w2rb[4 * i], a1);
                    a1 = fmaf(v.y, w2rb[4 * i + 1], a1);
                    a1 = fmaf(v.z, w2rb[4 * i + 2], a1);
                    a1 = fmaf(v.w, w2rb[4 * i + 3], a1);
                }
                m0 = fmaxf(m0, fmaxf(a0, 0.0f));
                m1 = fmaxf(m1, fmaxf(a1, 0.0f));
            }

            out_pts[(size_t)b * 128 * NSAMP + (size_t)lane * NSAMP + sq]        = m0;
            out_pts[(size_t)b * 128 * NSAMP + (size_t)(lane + 64) * NSAMP + sq] = m1;
        }
    }
}

extern "C" void kernel_launch(void* const* d_in, const int* in_sizes, int n_in,
                              void* d_out, int out_size, void* d_ws, size_t ws_size,
                              hipStream_t stream) {
    const float* xyz      = (const float*)d_in[0];
    const float* features = (const float*)d_in[1];
    const float* W1       = (const float*)d_in[2];
    const float* b1       = (const float*)d_in[3];
    const float* W2       = (const float*)d_in[4];
    const float* b2       = (const float*)d_in[5];

    float* out_xyz = (float*)d_out;                                  // [B,3,S]
    float* out_pts = (float*)d_out + (size_t)BATCH * 3 * NSAMP;      // [B,128,S]

    unsigned long long* pub = (unsigned long long*)d_ws;             // [B,S,3]

    fused_kernel<<<BATCH + NWBLK, THREADS, 0, stream>>>(
        xyz, features, W1, b1, W2, b2, out_xyz, out_pts, pub);
}